// Round 9
// baseline (1643.644 us; speedup 1.0000x reference)
//
#include <hip/hip_runtime.h>
#include <math.h>

typedef __attribute__((ext_vector_type(2))) float f32x2;
typedef __attribute__((ext_vector_type(4))) float f32x4;

#define MAX_DELAY 128
#define INPUT 64
#define HIDDEN 128
#define HALF 64
#define OUT 64
#define BATCH 32
#define T 128
#define OUT_LEN 64
#define NTHR 1024   // 16 waves: waves 0-7 = batch 2b, waves 8-15 = batch 2b+1

static __device__ __forceinline__ f32x2 splat2(float v) { f32x2 r; r.x = v; r.y = v; return r; }
static __device__ __forceinline__ f32x4 splat4(float v) { f32x4 r; r.x = v; r.y = v; r.z = v; r.w = v; return r; }

static __device__ __forceinline__ f32x2 pk_fma(f32x2 a, f32x2 b, f32x2 c) {
    f32x2 d;
    asm("v_pk_fma_f32 %0, %1, %2, %3" : "=v"(d) : "v"(a), "v"(b), "v"(c));
    return d;
}
static __device__ __forceinline__ f32x2 pk_fma_n0(f32x2 a, f32x2 b, f32x2 c) { // -a*b + c
    f32x2 d;
    asm("v_pk_fma_f32 %0, %1, %2, %3 neg_lo:[1,0,0] neg_hi:[1,0,0]"
        : "=v"(d) : "v"(a), "v"(b), "v"(c));
    return d;
}
static __device__ __forceinline__ f32x2 pk_add(f32x2 a, f32x2 b) {
    f32x2 d;
    asm("v_pk_add_f32 %0, %1, %2" : "=v"(d) : "v"(a), "v"(b));
    return d;
}
static __device__ __forceinline__ f32x2 lo2(f32x4 v) { f32x2 r; r.x = v.x; r.y = v.y; return r; }
static __device__ __forceinline__ f32x2 hi2(f32x4 v) { f32x2 r; r.x = v.z; r.y = v.w; return r; }

template <int N>
static __device__ __forceinline__ float dotN(const f32x4 (&w)[N], const f32x4* v) {
    f32x2 a0 = splat2(0.f), a1 = splat2(0.f), a2 = splat2(0.f), a3 = splat2(0.f);
#pragma unroll
    for (int j = 0; j < N; ++j) {
        const f32x4 wv = w[j], vv = v[j];
        if (j & 1) { a2 = pk_fma(lo2(wv), lo2(vv), a2); a3 = pk_fma(hi2(wv), hi2(vv), a3); }
        else       { a0 = pk_fma(lo2(wv), lo2(vv), a0); a1 = pk_fma(hi2(wv), hi2(vv), a1); }
    }
    const f32x2 s = pk_add(pk_add(a0, a1), pk_add(a2, a3));
    return s.x + s.y;
}

// DPP cross-lane (1-cycle VALU).
template <int CTRL>
static __device__ __forceinline__ float dpp_movf(float v) {
    return __int_as_float(__builtin_amdgcn_update_dpp(
        0, __float_as_int(v), CTRL, 0xF, 0xF, true));
}
#define DPP_XOR1 0xB1  // quad_perm [1,0,3,2]
#define DPP_XOR2 0x4E  // quad_perm [2,3,0,1]
#define DPP_ROT1 0x39  // quad_perm [1,2,3,0] (lane i <- i+1 mod 4)
#define DPP_MIR8 0x141 // row_half_mirror

// msg LDS pad: stride-24 per 16 floats (conflict-free, x4-aligned)
#define PAD16(k) ((k) + (((k) >> 4) << 3))
// heads LDS pad: +4 floats per 32 -> quad streams hit disjoint bank groups
#define PADH(k)  ((k) + (((k) >> 5) << 2))

// DUAL-BATCH per block (structural probe): R7 body per 512-thread group,
// two independent recurrence chains co-scheduled through shared barriers.
// 16 blocks x 1024 thr -> 4 FULL-THICKNESS waves/SIMD from 2 independent
// chains fill the ~60% idle issue slots (R8 proved 1 wave/SIMD exposes
// latency; R3 proved thin waves don't help; this adds waves WITHOUT thinning).
__global__ __attribute__((amdgpu_waves_per_eu(4, 4))) __launch_bounds__(NTHR)
void delayrnn_kernel(
    const float* __restrict__ x,        // (B, T, INPUT)
    const int*   __restrict__ lengths,  // (B)
    const float* __restrict__ Wm,       // (INPUT+HIDDEN, HIDDEN)
    const float* __restrict__ bm,       // (HIDDEN)
    const float* __restrict__ W1,       // (HIDDEN, HALF)
    const float* __restrict__ b1,       // (HALF)
    const float* __restrict__ W2,       // (HALF, 2*HIDDEN)
    const float* __restrict__ b2,       // (2*HIDDEN)
    const float* __restrict__ Wo,       // (HIDDEN, OUT)
    const float* __restrict__ bo,       // (OUT)
    float* __restrict__ out)            // (B, OUT_LEN, OUT)
{
    const int tid = threadIdx.x;
    const int g   = tid >> 9;            // batch group (0/1) = waves 0-7 / 8-15
    const int t2  = tid & 511;           // thread id within group
    const int len0 = lengths[blockIdx.x * 2];
    const int len1 = lengths[blockIdx.x * 2 + 1];
    const int b    = blockIdx.x * 2 + g;
    const int len  = g ? len1 : len0;
    const int total = len + OUT_LEN;
    const int itermax = ((len0 > len1) ? len0 : len1) + OUT_LEN;

    const int h  = t2 >> 2, q  = t2 & 3;   // channel h: quad of 4 lanes
    const int qq = q & 1,    qh = q >> 1;    // tau/mem roles within the quad
    const int k1 = t2 >> 3, r1 = t2 & 7;   // h1: 8 lanes/out
    const int co = t2 >> 3, ro = t2 & 7;   // out-proj: 8 lanes/out
    const int c2 = h + 128 * qh;             // qh=0: tau col, qh=1: mem col

    // ---- weights -> registers (all f32; per-wave identical to R7) ----
    f32x4 wmh[8];                       // msg heads-part: rows 64 + [q*32, q*32+32)
#pragma unroll
    for (int j = 0; j < 8; ++j) {
        wmh[j].x = Wm[(64 + q * 32 + 4 * j    ) * HIDDEN + h];
        wmh[j].y = Wm[(64 + q * 32 + 4 * j + 1) * HIDDEN + h];
        wmh[j].z = Wm[(64 + q * 32 + 4 * j + 2) * HIDDEN + h];
        wmh[j].w = Wm[(64 + q * 32 + 4 * j + 3) * HIDDEN + h];
    }
    f32x4 wmx[4];                       // msg x-part: rows [q*16, q*16+16)
#pragma unroll
    for (int j = 0; j < 4; ++j) {
        wmx[j].x = Wm[(q * 16 + 4 * j    ) * HIDDEN + h];
        wmx[j].y = Wm[(q * 16 + 4 * j + 1) * HIDDEN + h];
        wmx[j].z = Wm[(q * 16 + 4 * j + 2) * HIDDEN + h];
        wmx[j].w = Wm[(q * 16 + 4 * j + 3) * HIDDEN + h];
    }
    f32x4 w14[4];                       // h1: K-slice [r1*16, r1*16+16)
#pragma unroll
    for (int j = 0; j < 4; ++j) {
        w14[j].x = W1[(r1 * 16 + 4 * j    ) * HALF + k1];
        w14[j].y = W1[(r1 * 16 + 4 * j + 1) * HALF + k1];
        w14[j].z = W1[(r1 * 16 + 4 * j + 2) * HALF + k1];
        w14[j].w = W1[(r1 * 16 + 4 * j + 3) * HALF + k1];
    }
    f32x4 w24[8];                       // tau/mem: K-slice [qq*32, qq*32+32)
#pragma unroll
    for (int j = 0; j < 8; ++j) {
        w24[j].x = W2[(qq * 32 + 4 * j    ) * (2 * HIDDEN) + c2];
        w24[j].y = W2[(qq * 32 + 4 * j + 1) * (2 * HIDDEN) + c2];
        w24[j].z = W2[(qq * 32 + 4 * j + 2) * (2 * HIDDEN) + c2];
        w24[j].w = W2[(qq * 32 + 4 * j + 3) * (2 * HIDDEN) + c2];
    }
    f32x4 wo4[4];                       // out: K-slice [ro*16, ro*16+16)
#pragma unroll
    for (int m = 0; m < 4; ++m) {
        wo4[m].x = Wo[(ro * 16 + 4 * m    ) * OUT + co];
        wo4[m].y = Wo[(ro * 16 + 4 * m + 1) * OUT + co];
        wo4[m].z = Wo[(ro * 16 + 4 * m + 2) * OUT + co];
        wo4[m].w = Wo[(ro * 16 + 4 * m + 3) * OUT + co];
    }
    const float bm_r = bm[h];
    const float b1_r = b1[k1];
    const float b2_r = b2[c2];
    const float bo_r = bo[co];

    // delay-buffer slice: channel h, delays q*32 .. q*32+31
    f32x2 buf2[16];
#pragma unroll
    for (int d = 0; d < 16; ++d) { buf2[d].x = 0.f; buf2[d].y = 0.f; }

    __shared__ f32x4 s_x4[2][T * INPUT / 4];   // 2 x 32 KB staged input
    __shared__ float s_vh[2][140];             // heads, PADH layout
    __shared__ f32x4 s_msg4[2][48];            // msg f32, stride-24 per 16
    __shared__ float s_h1[2][HALF];
    __shared__ f32x4 s_out4[2][OUT_LEN * OUT / 4];  // 2 x 16 KB decode stash

    {
        const f32x4* xg4 = (const f32x4*)x;
        for (int idx = t2; idx < T * INPUT / 4; idx += 512)
            s_x4[g][idx] = xg4[b * (T * INPUT / 4) + idx];
        if (t2 < 35) ((f32x4*)s_vh[g])[t2] = splat4(0.f);   // heads = 0
    }
    __syncthreads();                        // B1 (iter 0)

    // preamble: x-part partial for step 0
    float px = 0.f;
    if (0 < len) px = dotN<4>(wmx, s_x4[g] + q * 4);

    const float ivb = (float)q * 0.25f;     // (q*32)/128
    float msg_p = 0.f, tau_p = 0.f, mem_p = 0.f;  // deferred-blend state (i=0: no-op)

    for (int i = 0; i < itermax; ++i) {
        // ============ phase 1: heads dot (+ deferred blend of step i-1) ============
        if (i < total) {
            const f32x4* v4 = (const f32x4*)(s_vh[g] + q * 36);
            const float pdot = dotN<8>(wmh, v4);

            // ---- deferred blend of step i-1 (fills the LDS-read stall) ----
            {
                float tail_in = dpp_movf<DPP_ROT1>(buf2[0].x);   // neighbor q+1's old head
                if (q == 3) tail_in = 0.f;                       // shift-in zero at d=127
                const float taup = tau_p - ivb;
                f32x2 t2v; t2v.x = taup; t2v.y = taup - (1.f / MAX_DELAY);
                const f32x2 st2  = splat2(-2.f / MAX_DELAY);
                const f32x2 mem2 = splat2(mem_p);
                const f32x2 m2m  = splat2(-2.f * mem_p);
                const f32x2 msg2 = splat2(msg_p);
#pragma unroll
                for (int d = 0; d < 16; ++d) {
                    f32x2 nb;
                    nb.x = buf2[d].y;
                    nb.y = (d < 15) ? buf2[d + 1].x : tail_in;
                    f32x2 a  = __builtin_elementwise_max(t2v, -t2v);  // |tau' - d/128|
                    f32x2 f1 = pk_fma(a, mem2, m2m);                  // a*mem - 2mem
                    f32x2 iw = pk_fma(a, f1, mem2);                   // mem*(1-a)^2
                    f32x2 u  = pk_fma(iw, msg2, nb);                  // iw*msg + nb
                    buf2[d]  = pk_fma_n0(iw, nb, u);                  // nb + iw*(msg-nb)
                    t2v = pk_add(t2v, st2);
                }
            }

            float p = pdot + px;                        // + lookahead x-part
            p += dpp_movf<DPP_XOR1>(p);
            p += dpp_movf<DPP_XOR2>(p);                 // all 4 lanes: full K=192 dot
            const float z  = p + bm_r;
            const float e2 = __expf(2.f * z);
            const float msg = 1.f - 2.f * __builtin_amdgcn_rcpf(e2 + 1.f);  // tanh
            if (q == 0) ((float*)s_msg4[g])[PAD16(h)] = msg;
            msg_p = msg;
        }
        __syncthreads();                            // B2: msg visible block-wide

        // ============ phase 2: h1 + x-lookahead + out-stash ============
        if (i < total) {
            {
                const f32x4* m4 = (const f32x4*)((const float*)s_msg4[g] + r1 * 24);
                float p1 = dotN<4>(w14, m4);
                p1 += dpp_movf<DPP_XOR1>(p1);
                p1 += dpp_movf<DPP_XOR2>(p1);
                p1 += dpp_movf<DPP_MIR8>(p1);           // 8-lane allreduce
                if (r1 == 0) s_h1[g][k1] = fmaxf(p1 + b1_r, 0.f);
            }

            // ---- x-part lookahead for step i+1 (fills h1 stall) ----
            px = 0.f;
            if (i + 1 < len) px = dotN<4>(wmx, s_x4[g] + (i + 1) * 16 + q * 4);

            // ---- decode out-projection -> LDS stash ----
            if (i >= len) {
                const f32x4* mo4 = (const f32x4*)((const float*)s_msg4[g] + ro * 24);
                float po = dotN<4>(wo4, mo4);
                po += dpp_movf<DPP_XOR1>(po);
                po += dpp_movf<DPP_XOR2>(po);
                po += dpp_movf<DPP_MIR8>(po);
                if (ro == 0) ((float*)s_out4[g])[(i - len) * OUT + co] = po + bo_r;
            }
        }
        __syncthreads();                            // B3: h1 visible block-wide

        // ============ phase 3: tau/mem + head only (blend deferred) ============
        if (i < total) {
            const f32x4* hh4 = (const f32x4*)(s_h1[g] + (qq << 5));
            float pt = dotN<8>(w24, hh4);
            pt += dpp_movf<DPP_XOR1>(pt);            // K-halves combined
            const float own = __builtin_amdgcn_rcpf(1.f + __expf(-(pt + b2_r)));
            const float oth = dpp_movf<DPP_XOR2>(own);
            const float tau_r = qh ? oth : own;
            const float mem_r = qh ? own : oth;
            tau_p = tau_r; mem_p = mem_r;

            // head (global delay 0) from post-blend(i-1) buf[1]; blend deferred
            const float nb0 = buf2[0].y;
            const float iw0 = tau_r * (tau_r * mem_r - 2.f * mem_r) + mem_r;  // mem*(1-tau)^2
            const float head = iw0 * (msg_p - nb0) + nb0;
            if (q == 0) s_vh[g][PADH(h)] = head;
        }
        __syncthreads();                            // B1 (next iter)
    }

    // ---- bulk store decode outputs (coalesced, per group) ----
    {
        f32x4* og4 = (f32x4*)(out + b * OUT_LEN * OUT);
        og4[t2]       = s_out4[g][t2];
        og4[t2 + 512] = s_out4[g][t2 + 512];
    }
}

extern "C" void kernel_launch(void* const* d_in, const int* in_sizes, int n_in,
                              void* d_out, int out_size, void* d_ws, size_t ws_size,
                              hipStream_t stream) {
    const float* x       = (const float*)d_in[0];
    const int*   lengths = (const int*)  d_in[1];
    // d_in[2] = out_lengths scalar (compile-time 64)
    const float* Wm = (const float*)d_in[3];
    const float* bm = (const float*)d_in[4];
    const float* W1 = (const float*)d_in[5];
    const float* b1 = (const float*)d_in[6];
    const float* W2 = (const float*)d_in[7];
    const float* b2 = (const float*)d_in[8];
    const float* Wo = (const float*)d_in[9];
    const float* bo = (const float*)d_in[10];
    float* out = (float*)d_out;

    delayrnn_kernel<<<BATCH / 2, NTHR, 0, stream>>>(
        x, lengths, Wm, bm, W1, b1, W2, b2, Wo, bo, out);
}

// Round 10
// 436.638 us; speedup vs baseline: 3.7643x; 3.7643x over previous
//
#include <hip/hip_runtime.h>
#include <math.h>

typedef __attribute__((ext_vector_type(2))) float f32x2;
typedef __attribute__((ext_vector_type(4))) float f32x4;

#define MAX_DELAY 128
#define INPUT 64
#define HIDDEN 128
#define HALF 64
#define OUT 64
#define BATCH 32
#define T 128
#define OUT_LEN 64
#define NTHR 512

static __device__ __forceinline__ f32x2 splat2(float v) { f32x2 r; r.x = v; r.y = v; return r; }
static __device__ __forceinline__ f32x4 splat4(float v) { f32x4 r; r.x = v; r.y = v; r.z = v; r.w = v; return r; }

static __device__ __forceinline__ f32x2 pk_fma(f32x2 a, f32x2 b, f32x2 c) {
    f32x2 d;
    asm("v_pk_fma_f32 %0, %1, %2, %3" : "=v"(d) : "v"(a), "v"(b), "v"(c));
    return d;
}
static __device__ __forceinline__ f32x2 pk_fma_n0(f32x2 a, f32x2 b, f32x2 c) { // -a*b + c
    f32x2 d;
    asm("v_pk_fma_f32 %0, %1, %2, %3 neg_lo:[1,0,0] neg_hi:[1,0,0]"
        : "=v"(d) : "v"(a), "v"(b), "v"(c));
    return d;
}
static __device__ __forceinline__ f32x2 pk_add(f32x2 a, f32x2 b) {
    f32x2 d;
    asm("v_pk_add_f32 %0, %1, %2" : "=v"(d) : "v"(a), "v"(b));
    return d;
}
static __device__ __forceinline__ f32x2 lo2(f32x4 v) { f32x2 r; r.x = v.x; r.y = v.y; return r; }
static __device__ __forceinline__ f32x2 hi2(f32x4 v) { f32x2 r; r.x = v.z; r.y = v.w; return r; }

template <int N>
static __device__ __forceinline__ float dotN(const f32x4 (&w)[N], const f32x4* v) {
    f32x2 a0 = splat2(0.f), a1 = splat2(0.f), a2 = splat2(0.f), a3 = splat2(0.f);
#pragma unroll
    for (int j = 0; j < N; ++j) {
        const f32x4 wv = w[j], vv = v[j];
        if (j & 1) { a2 = pk_fma(lo2(wv), lo2(vv), a2); a3 = pk_fma(hi2(wv), hi2(vv), a3); }
        else       { a0 = pk_fma(lo2(wv), lo2(vv), a0); a1 = pk_fma(hi2(wv), hi2(vv), a1); }
    }
    const f32x2 s = pk_add(pk_add(a0, a1), pk_add(a2, a3));
    return s.x + s.y;
}

// DPP cross-lane (1-cycle VALU).
template <int CTRL>
static __device__ __forceinline__ float dpp_movf(float v) {
    return __int_as_float(__builtin_amdgcn_update_dpp(
        0, __float_as_int(v), CTRL, 0xF, 0xF, true));
}
#define DPP_XOR1 0xB1  // quad_perm [1,0,3,2]
#define DPP_XOR2 0x4E  // quad_perm [2,3,0,1]
#define DPP_ROT1 0x39  // quad_perm [1,2,3,0] (lane i <- i+1 mod 4)
#define DPP_MIR8 0x141 // row_half_mirror

// msg LDS pad: stride-24 per 16 floats (conflict-free, x4-aligned)
#define PAD16(k) ((k) + (((k) >> 4) << 3))
// heads LDS pad: +4 floats per 32 -> quad streams hit disjoint bank groups
#define PADH(k)  ((k) + (((k) >> 5) << 2))

// TWO-BARRIER structure (from R6's 3-barrier best, exact f32):
//  h1 is computed as CROSS-WAVE PARTIAL SUMS: wave w reads back its OWN 16 msg
//  values from LDS (in-wave program order, no barrier), computes
//  partial[k] = sum_{h in wave} W1[h,k]*msg[h] for its lane's k, and
//  ds_add_f32's into h1acc[parity][k]. B2 then publishes BOTH msg (out-proj)
//  and the completed h1acc (tau/mem) -> the old B3 barrier disappears.
//  h1acc is parity-double-buffered and b1-SEEDED one iteration ahead (the
//  seed is 2 barriers away from the adds it precedes -> race-free), so
//  consumers just apply relu(acc).
__global__ __attribute__((amdgpu_waves_per_eu(2, 2))) __launch_bounds__(NTHR)
void delayrnn_kernel(
    const float* __restrict__ x,        // (B, T, INPUT)
    const int*   __restrict__ lengths,  // (B)
    const float* __restrict__ Wm,       // (INPUT+HIDDEN, HIDDEN)
    const float* __restrict__ bm,       // (HIDDEN)
    const float* __restrict__ W1,       // (HIDDEN, HALF)
    const float* __restrict__ b1,       // (HALF)
    const float* __restrict__ W2,       // (HALF, 2*HIDDEN)
    const float* __restrict__ b2,       // (2*HIDDEN)
    const float* __restrict__ Wo,       // (HIDDEN, OUT)
    const float* __restrict__ bo,       // (OUT)
    float* __restrict__ out)            // (B, OUT_LEN, OUT)
{
    const int b   = blockIdx.x;
    const int tid = threadIdx.x;
    const int len = lengths[b];
    const int total = len + OUT_LEN;

    const int h  = tid >> 2, q  = tid & 3;   // channel h: quad of 4 lanes
    const int qq = q & 1,    qh = q >> 1;    // tau/mem roles within the quad
    const int wv = tid >> 6, ln = tid & 63;  // wave id, lane id (lane owns h1 k=ln)
    const int co = tid >> 3, ro = tid & 7;   // out-proj: 8 lanes/out
    const int c2 = h + 128 * qh;             // qh=0: tau col, qh=1: mem col

    // ---- weights -> registers (all f32) ----
    f32x4 wmh[8];                       // msg heads-part: rows 64 + [q*32, q*32+32)
#pragma unroll
    for (int j = 0; j < 8; ++j) {
        wmh[j].x = Wm[(64 + q * 32 + 4 * j    ) * HIDDEN + h];
        wmh[j].y = Wm[(64 + q * 32 + 4 * j + 1) * HIDDEN + h];
        wmh[j].z = Wm[(64 + q * 32 + 4 * j + 2) * HIDDEN + h];
        wmh[j].w = Wm[(64 + q * 32 + 4 * j + 3) * HIDDEN + h];
    }
    f32x4 wmx[4];                       // msg x-part: rows [q*16, q*16+16)
#pragma unroll
    for (int j = 0; j < 4; ++j) {
        wmx[j].x = Wm[(q * 16 + 4 * j    ) * HIDDEN + h];
        wmx[j].y = Wm[(q * 16 + 4 * j + 1) * HIDDEN + h];
        wmx[j].z = Wm[(q * 16 + 4 * j + 2) * HIDDEN + h];
        wmx[j].w = Wm[(q * 16 + 4 * j + 3) * HIDDEN + h];
    }
    f32x2 w1s[8];                       // h1 partial: W1[16wv+2j .. +2, ln]
#pragma unroll
    for (int j = 0; j < 8; ++j) {
        w1s[j].x = W1[(16 * wv + 2 * j    ) * HALF + ln];
        w1s[j].y = W1[(16 * wv + 2 * j + 1) * HALF + ln];
    }
    f32x4 w24[8];                       // tau/mem: K-slice [qq*32, qq*32+32)
#pragma unroll
    for (int j = 0; j < 8; ++j) {
        w24[j].x = W2[(qq * 32 + 4 * j    ) * (2 * HIDDEN) + c2];
        w24[j].y = W2[(qq * 32 + 4 * j + 1) * (2 * HIDDEN) + c2];
        w24[j].z = W2[(qq * 32 + 4 * j + 2) * (2 * HIDDEN) + c2];
        w24[j].w = W2[(qq * 32 + 4 * j + 3) * (2 * HIDDEN) + c2];
    }
    f32x4 wo4[4];                       // out: K-slice [ro*16, ro*16+16)
#pragma unroll
    for (int m = 0; m < 4; ++m) {
        wo4[m].x = Wo[(ro * 16 + 4 * m    ) * OUT + co];
        wo4[m].y = Wo[(ro * 16 + 4 * m + 1) * OUT + co];
        wo4[m].z = Wo[(ro * 16 + 4 * m + 2) * OUT + co];
        wo4[m].w = Wo[(ro * 16 + 4 * m + 3) * OUT + co];
    }
    const float bm_r = bm[h];
    const float b1z = b1[ln];            // for parity-seed (wave 0 writes)
    const float b2_r = b2[c2];
    const float bo_r = bo[co];

    // delay-buffer slice: channel h, delays q*32 .. q*32+31
    f32x2 buf2[16];
#pragma unroll
    for (int d = 0; d < 16; ++d) { buf2[d].x = 0.f; buf2[d].y = 0.f; }

    __shared__ f32x4 s_x4[T * INPUT / 4];   // 32 KB staged input
    __shared__ float s_vh[140];             // heads, PADH layout (conflict-free)
    __shared__ float s_msg[192];            // msg f32, stride-24 per 16 (PAD16)
    __shared__ float s_h1acc[2][HALF];      // parity-buffered h1 accumulators
    __shared__ f32x4 s_out4[OUT_LEN * OUT / 4];  // 16 KB decode-output stash

    {
        const f32x4* xg4 = (const f32x4*)x;
        for (int idx = tid; idx < T * INPUT / 4; idx += NTHR)
            s_x4[idx] = xg4[b * (T * INPUT / 4) + idx];
        if (tid < 35) ((f32x4*)s_vh)[tid] = splat4(0.f);   // heads = 0 (140 floats)
        if (tid < 64) s_h1acc[0][tid] = b1z;               // seed parity 0
    }
    __syncthreads();                        // B1 (iter 0)

    // preamble: x-part partial for step 0
    float px = 0.f;
    if (0 < len) px = dotN<4>(wmx, s_x4 + q * 4);

    const float ivb = (float)q * 0.25f;     // (q*32)/128
    float msg_p = 0.f, tau_p = 0.f, mem_p = 0.f;  // deferred-blend state (i=0: no-op)

    for (int i = 0; i < total; ++i) {
        const int par = i & 1;

        // ============ P1: msg dot + blend(i-1) + in-wave h1 partial ============
        // seed NEXT iteration's h1acc with b1 (2 barriers before its adds)
        if (tid < 64) s_h1acc[par ^ 1][ln] = b1z;

        const f32x4* v4 = (const f32x4*)(s_vh + q * 36);
        const float pdot = dotN<8>(wmh, v4);

        // ---- deferred blend of step i-1 (fills heads-read + msg round-trips) ----
        {
            float tail_in = dpp_movf<DPP_ROT1>(buf2[0].x);   // neighbor q+1's old head
            if (q == 3) tail_in = 0.f;                       // shift-in zero at d=127
            const float taup = tau_p - ivb;
            f32x2 t2; t2.x = taup; t2.y = taup - (1.f / MAX_DELAY);
            const f32x2 st2  = splat2(-2.f / MAX_DELAY);
            const f32x2 mem2 = splat2(mem_p);
            const f32x2 m2m  = splat2(-2.f * mem_p);
            const f32x2 msg2 = splat2(msg_p);
#pragma unroll
            for (int d = 0; d < 16; ++d) {
                f32x2 nb;
                nb.x = buf2[d].y;
                nb.y = (d < 15) ? buf2[d + 1].x : tail_in;
                f32x2 a  = __builtin_elementwise_max(t2, -t2);   // |tau' - d/128|
                f32x2 f1 = pk_fma(a, mem2, m2m);                 // a*mem - 2mem
                f32x2 iw = pk_fma(a, f1, mem2);                  // mem*(1-a)^2
                f32x2 u  = pk_fma(iw, msg2, nb);                 // iw*msg + nb
                buf2[d]  = pk_fma_n0(iw, nb, u);                 // nb + iw*(msg-nb)
                t2 = pk_add(t2, st2);
            }
        }

        float p = pdot + px;                        // + lookahead x-part
        p += dpp_movf<DPP_XOR1>(p);
        p += dpp_movf<DPP_XOR2>(p);                 // all 4 lanes: full K=192 dot
        const float z  = p + bm_r;
        const float e2 = __expf(2.f * z);
        const float msg = 1.f - 2.f * __builtin_amdgcn_rcpf(e2 + 1.f);  // tanh
        if (q == 0) s_msg[PAD16(h)] = msg;
        msg_p = msg;

        // ---- in-wave h1 partial: read back OWN wave's 16 msg (no barrier;
        //      in-wave lgkmcnt orders write->read), 8 pk_fma, one ds_add_f32 ----
        {
            const f32x2* m2 = (const f32x2*)(s_msg + 24 * wv);
            f32x2 acc0 = pk_fma(w1s[0], m2[0], splat2(0.f));
            f32x2 acc1 = pk_fma(w1s[1], m2[1], splat2(0.f));
            acc0 = pk_fma(w1s[2], m2[2], acc0);
            acc1 = pk_fma(w1s[3], m2[3], acc1);
            acc0 = pk_fma(w1s[4], m2[4], acc0);
            acc1 = pk_fma(w1s[5], m2[5], acc1);
            acc0 = pk_fma(w1s[6], m2[6], acc0);
            acc1 = pk_fma(w1s[7], m2[7], acc1);
            const f32x2 s = pk_add(acc0, acc1);
            atomicAdd(&s_h1acc[par][ln], s.x + s.y);
        }
        __syncthreads();                            // B2: msg + h1acc complete

        // ============ P2: tau/mem + head + out-proj + x-lookahead ============
        {
            const f32x4* hh4 = (const f32x4*)(s_h1acc[par] + (qq << 5));
            const f32x4 z4 = splat4(0.f);
            f32x2 a0 = splat2(0.f), a1 = splat2(0.f), a2 = splat2(0.f), a3 = splat2(0.f);
#pragma unroll
            for (int j = 0; j < 8; ++j) {
                const f32x4 hr = __builtin_elementwise_max(hh4[j], z4);  // relu(b1+acc)
                const f32x4 wvv = w24[j];
                if (j & 1) { a2 = pk_fma(lo2(wvv), lo2(hr), a2); a3 = pk_fma(hi2(wvv), hi2(hr), a3); }
                else       { a0 = pk_fma(lo2(wvv), lo2(hr), a0); a1 = pk_fma(hi2(wvv), hi2(hr), a1); }
            }
            const f32x2 ssum = pk_add(pk_add(a0, a1), pk_add(a2, a3));
            float pt = ssum.x + ssum.y;
            pt += dpp_movf<DPP_XOR1>(pt);            // K-halves combined
            const float own = __builtin_amdgcn_rcpf(1.f + __expf(-(pt + b2_r)));
            const float oth = dpp_movf<DPP_XOR2>(own);
            const float tau_r = qh ? oth : own;
            const float mem_r = qh ? own : oth;
            tau_p = tau_r; mem_p = mem_r;

            // head (global delay 0) from post-blend(i-1) buf[1]; blend deferred
            const float nb0 = buf2[0].y;
            const float iw0 = tau_r * (tau_r * mem_r - 2.f * mem_r) + mem_r;  // mem*(1-tau)^2
            const float head = iw0 * (msg_p - nb0) + nb0;
            if (q == 0) s_vh[PADH(h)] = head;
        }

        // ---- decode out-projection -> LDS stash (needs all msg; post-B2) ----
        if (i >= len) {
            const f32x4* mo4 = (const f32x4*)(s_msg + ro * 24);
            float po = dotN<4>(wo4, mo4);
            po += dpp_movf<DPP_XOR1>(po);
            po += dpp_movf<DPP_XOR2>(po);
            po += dpp_movf<DPP_MIR8>(po);
            if (ro == 0) ((float*)s_out4)[(i - len) * OUT + co] = po + bo_r;
        }

        // ---- x-part lookahead for step i+1 (independent filler) ----
        px = 0.f;
        if (i + 1 < len) px = dotN<4>(wmx, s_x4 + (i + 1) * 16 + q * 4);

        __syncthreads();                            // B1 (next iter)
    }

    // ---- bulk store decode outputs (coalesced) ----
    {
        f32x4* og4 = (f32x4*)(out + b * OUT_LEN * OUT);
        og4[tid]        = s_out4[tid];
        og4[tid + NTHR] = s_out4[tid + NTHR];
    }
}

extern "C" void kernel_launch(void* const* d_in, const int* in_sizes, int n_in,
                              void* d_out, int out_size, void* d_ws, size_t ws_size,
                              hipStream_t stream) {
    const float* x       = (const float*)d_in[0];
    const int*   lengths = (const int*)  d_in[1];
    // d_in[2] = out_lengths scalar (compile-time 64)
    const float* Wm = (const float*)d_in[3];
    const float* bm = (const float*)d_in[4];
    const float* W1 = (const float*)d_in[5];
    const float* b1 = (const float*)d_in[6];
    const float* W2 = (const float*)d_in[7];
    const float* b2 = (const float*)d_in[8];
    const float* Wo = (const float*)d_in[9];
    const float* bo = (const float*)d_in[10];
    float* out = (float*)d_out;

    delayrnn_kernel<<<BATCH, NTHR, 0, stream>>>(
        x, lengths, Wm, bm, W1, b1, W2, b2, Wo, bo, out);
}

// Round 11
// 310.224 us; speedup vs baseline: 5.2983x; 1.4075x over previous
//
#include <hip/hip_runtime.h>
#include <math.h>

typedef __attribute__((ext_vector_type(2))) float f32x2;
typedef __attribute__((ext_vector_type(4))) float f32x4;

#define MAX_DELAY 128
#define INPUT 64
#define HIDDEN 128
#define HALF 64
#define OUT 64
#define BATCH 32
#define T 128
#define OUT_LEN 64
#define NTHR 512

static __device__ __forceinline__ f32x2 splat2(float v) { f32x2 r; r.x = v; r.y = v; return r; }
static __device__ __forceinline__ f32x4 splat4(float v) { f32x4 r; r.x = v; r.y = v; r.z = v; r.w = v; return r; }

// DPP cross-lane (1-cycle VALU).
template <int CTRL>
static __device__ __forceinline__ float dpp_movf(float v) {
    return __int_as_float(__builtin_amdgcn_update_dpp(
        0, __float_as_int(v), CTRL, 0xF, 0xF, true));
}
#define DPP_XOR1 0xB1  // quad_perm [1,0,3,2]
#define DPP_XOR2 0x4E  // quad_perm [2,3,0,1]
#define DPP_ROT1 0x39  // quad_perm [1,2,3,0] (lane i <- i+1 mod 4)
#define DPP_MIR8 0x141 // row_half_mirror

// msg LDS pad: stride-24 per 16 floats (conflict-free, x4-aligned)
#define PAD16(k) ((k) + (((k) >> 4) << 3))
// heads LDS pad: +4 floats per 32 -> quad streams hit disjoint bank groups
#define PADH(k)  ((k) + (((k) >> 5) << 2))

// BEST-MEASURED STRUCTURE (session floor: 243.9 us dispatch).
// 512 thr / 8 waves (2/SIMD), 3 barriers/step — the minimum for this dataflow's
// three all-to-all exchanges (heads->msg, msg->h1, h1->tau; relu/tanh block fusion).
// Probed and rejected: f16 redundant h1 (precision, R1), 16 thin waves (R3),
// phase rebalancing (R4/R5), packed-fp32 dots (R7), 1 wave/SIMD thick (R8),
// dual-batch (R9), LDS-atomic barrier merge (R10). Kept wins: deferred blend
// into P1's LDS-stall (R2), x-part lookahead + LDS out-stash + padded layouts
// (R4), waves_per_eu pin (R6).
__global__ __attribute__((amdgpu_waves_per_eu(2, 2))) __launch_bounds__(NTHR)
void delayrnn_kernel(
    const float* __restrict__ x,        // (B, T, INPUT)
    const int*   __restrict__ lengths,  // (B)
    const float* __restrict__ Wm,       // (INPUT+HIDDEN, HIDDEN)
    const float* __restrict__ bm,       // (HIDDEN)
    const float* __restrict__ W1,       // (HIDDEN, HALF)
    const float* __restrict__ b1,       // (HALF)
    const float* __restrict__ W2,       // (HALF, 2*HIDDEN)
    const float* __restrict__ b2,       // (2*HIDDEN)
    const float* __restrict__ Wo,       // (HIDDEN, OUT)
    const float* __restrict__ bo,       // (OUT)
    float* __restrict__ out)            // (B, OUT_LEN, OUT)
{
    const int b   = blockIdx.x;
    const int tid = threadIdx.x;
    const int len = lengths[b];
    const int total = len + OUT_LEN;

    const int h  = tid >> 2, q  = tid & 3;   // channel h: quad of 4 lanes
    const int qq = q & 1,    qh = q >> 1;    // tau/mem roles within the quad
    const int k1 = tid >> 3, r1 = tid & 7;   // h1: 8 lanes/out
    const int co = tid >> 3, ro = tid & 7;   // out-proj: 8 lanes/out
    const int c2 = h + 128 * qh;             // qh=0: tau col, qh=1: mem col

    // ---- weights -> registers (all f32) ----
    f32x4 wmh[8];                       // msg heads-part: rows 64 + [q*32, q*32+32)
#pragma unroll
    for (int j = 0; j < 8; ++j) {
        wmh[j].x = Wm[(64 + q * 32 + 4 * j    ) * HIDDEN + h];
        wmh[j].y = Wm[(64 + q * 32 + 4 * j + 1) * HIDDEN + h];
        wmh[j].z = Wm[(64 + q * 32 + 4 * j + 2) * HIDDEN + h];
        wmh[j].w = Wm[(64 + q * 32 + 4 * j + 3) * HIDDEN + h];
    }
    f32x4 wmx[4];                       // msg x-part: rows [q*16, q*16+16)
#pragma unroll
    for (int j = 0; j < 4; ++j) {
        wmx[j].x = Wm[(q * 16 + 4 * j    ) * HIDDEN + h];
        wmx[j].y = Wm[(q * 16 + 4 * j + 1) * HIDDEN + h];
        wmx[j].z = Wm[(q * 16 + 4 * j + 2) * HIDDEN + h];
        wmx[j].w = Wm[(q * 16 + 4 * j + 3) * HIDDEN + h];
    }
    f32x4 w14[4];                       // h1: K-slice [r1*16, r1*16+16)
#pragma unroll
    for (int j = 0; j < 4; ++j) {
        w14[j].x = W1[(r1 * 16 + 4 * j    ) * HALF + k1];
        w14[j].y = W1[(r1 * 16 + 4 * j + 1) * HALF + k1];
        w14[j].z = W1[(r1 * 16 + 4 * j + 2) * HALF + k1];
        w14[j].w = W1[(r1 * 16 + 4 * j + 3) * HALF + k1];
    }
    f32x4 w24[8];                       // tau/mem: K-slice [qq*32, qq*32+32)
#pragma unroll
    for (int j = 0; j < 8; ++j) {
        w24[j].x = W2[(qq * 32 + 4 * j    ) * (2 * HIDDEN) + c2];
        w24[j].y = W2[(qq * 32 + 4 * j + 1) * (2 * HIDDEN) + c2];
        w24[j].z = W2[(qq * 32 + 4 * j + 2) * (2 * HIDDEN) + c2];
        w24[j].w = W2[(qq * 32 + 4 * j + 3) * (2 * HIDDEN) + c2];
    }
    f32x4 wo4[4];                       // out: K-slice [ro*16, ro*16+16)
#pragma unroll
    for (int m = 0; m < 4; ++m) {
        wo4[m].x = Wo[(ro * 16 + 4 * m    ) * OUT + co];
        wo4[m].y = Wo[(ro * 16 + 4 * m + 1) * OUT + co];
        wo4[m].z = Wo[(ro * 16 + 4 * m + 2) * OUT + co];
        wo4[m].w = Wo[(ro * 16 + 4 * m + 3) * OUT + co];
    }
    const float bm_r = bm[h];
    const float b1_r = b1[k1];
    const float b2_r = b2[c2];
    const float bo_r = bo[co];

    // delay-buffer slice: channel h, delays q*32 .. q*32+31
    f32x2 buf2[16];
#pragma unroll
    for (int d = 0; d < 16; ++d) { buf2[d].x = 0.f; buf2[d].y = 0.f; }

    __shared__ f32x4 s_x4[T * INPUT / 4];   // 32 KB staged input
    __shared__ float s_vh[140];             // heads, PADH layout (conflict-free)
    __shared__ f32x4 s_msg4[48];            // msg f32, stride-24 per 16
    __shared__ float s_h1[HALF];
    __shared__ f32x4 s_out4[OUT_LEN * OUT / 4];  // 16 KB decode-output stash

    {
        const f32x4* xg4 = (const f32x4*)x;
        for (int idx = tid; idx < T * INPUT / 4; idx += NTHR)
            s_x4[idx] = xg4[b * (T * INPUT / 4) + idx];
        if (tid < 35) ((f32x4*)s_vh)[tid] = splat4(0.f);   // heads = 0 (140 floats)
    }
    __syncthreads();                        // B1 (iter 0)

    // preamble: x-part partial for step 0
    float px = 0.f;
    if (0 < len) {
        const f32x4* xs = s_x4 + q * 4;
        f32x4 t = (wmx[0] * xs[0] + wmx[2] * xs[2]) + (wmx[1] * xs[1] + wmx[3] * xs[3]);
        px = (t.x + t.z) + (t.y + t.w);
    }

    const float ivb = (float)q * 0.25f;     // (q*32)/128
    float msg_p = 0.f, tau_p = 0.f, mem_p = 0.f;  // deferred-blend state (i=0: no-op)

    for (int i = 0; i < total; ++i) {
        // ============ phase 1: heads dot (+ deferred blend of step i-1) ============
        const f32x4* v4 = (const f32x4*)(s_vh + q * 36);
        f32x4 a0 = wmh[0] * v4[0] + wmh[4] * v4[4];
        f32x4 a1 = wmh[1] * v4[1] + wmh[5] * v4[5];
        f32x4 a2 = wmh[2] * v4[2] + wmh[6] * v4[6];
        f32x4 a3 = wmh[3] * v4[3] + wmh[7] * v4[7];

        // ---- deferred blend of step i-1 (independent VALU; fills the LDS-read stall) ----
        {
            float tail_in = dpp_movf<DPP_ROT1>(buf2[0].x);   // neighbor q+1's old head
            if (q == 3) tail_in = 0.f;                       // shift-in zero at d=127
            const float taup = tau_p - ivb;
            f32x2 t2; t2.x = taup; t2.y = taup - (1.f / MAX_DELAY);
            const f32x2 st2  = splat2(-2.f / MAX_DELAY);
            const f32x2 mem2 = splat2(mem_p);
            const f32x2 m2m  = splat2(-2.f * mem_p);
            const f32x2 msg2 = splat2(msg_p);
#pragma unroll
            for (int d = 0; d < 16; ++d) {
                f32x2 nb;
                nb.x = buf2[d].y;
                nb.y = (d < 15) ? buf2[d + 1].x : tail_in;
                f32x2 a  = __builtin_elementwise_max(t2, -t2);   // |tau' - d/128|
                f32x2 f1 = a * mem2 + m2m;                       // a*mem - 2mem
                f32x2 iw = a * f1 + mem2;                        // mem*(1-a)^2
                f32x2 dd = msg2 - nb;
                buf2[d] = iw * dd + nb;
                t2 = t2 + st2;
            }
        }

        f32x4 s4 = (a0 + a1) + (a2 + a3);
        float p = (s4.x + s4.z) + (s4.y + s4.w) + px;   // + lookahead x-part
        p += dpp_movf<DPP_XOR1>(p);
        p += dpp_movf<DPP_XOR2>(p);                 // all 4 lanes: full K=192 dot
        const float z  = p + bm_r;
        const float e2 = __expf(2.f * z);
        const float msg = 1.f - 2.f * __builtin_amdgcn_rcpf(e2 + 1.f);  // tanh
        if (q == 0) ((float*)s_msg4)[PAD16(h)] = msg;
        msg_p = msg;
        __syncthreads();                            // B2: msg visible block-wide

        // ============ phase 2: h1 + x-lookahead + out-stash ============
        {
            const f32x4* m4 = (const f32x4*)((const float*)s_msg4 + r1 * 24);
            f32x4 cA = w14[0] * m4[0] + w14[2] * m4[2];
            f32x4 cB = w14[1] * m4[1] + w14[3] * m4[3];
            f32x4 cc = cA + cB;
            float p1 = (cc.x + cc.z) + (cc.y + cc.w);
            p1 += dpp_movf<DPP_XOR1>(p1);
            p1 += dpp_movf<DPP_XOR2>(p1);
            p1 += dpp_movf<DPP_MIR8>(p1);           // 8-lane allreduce
            if (r1 == 0) s_h1[k1] = fmaxf(p1 + b1_r, 0.f);
        }

        // ---- x-part lookahead for step i+1 (independent; fills h1 stall) ----
        px = 0.f;
        if (i + 1 < len) {
            const f32x4* xs = s_x4 + (i + 1) * 16 + q * 4;
            f32x4 t = (wmx[0] * xs[0] + wmx[2] * xs[2]) + (wmx[1] * xs[1] + wmx[3] * xs[3]);
            px = (t.x + t.z) + (t.y + t.w);
        }

        // ---- decode out-projection -> LDS stash (no global store in loop) ----
        if (i >= len) {
            const f32x4* mo4 = (const f32x4*)((const float*)s_msg4 + ro * 24);
            f32x4 oA = wo4[0] * mo4[0] + wo4[2] * mo4[2];
            f32x4 oB = wo4[1] * mo4[1] + wo4[3] * mo4[3];
            f32x4 oo = oA + oB;
            float po = (oo.x + oo.z) + (oo.y + oo.w);
            po += dpp_movf<DPP_XOR1>(po);
            po += dpp_movf<DPP_XOR2>(po);
            po += dpp_movf<DPP_MIR8>(po);
            if (ro == 0) ((float*)s_out4)[(i - len) * OUT + co] = po + bo_r;
        }
        __syncthreads();                            // B3: h1 visible block-wide

        // ============ phase 3: tau/mem + head only (blend deferred) ============
        {
            const f32x4* hh4 = (const f32x4*)(s_h1 + (qq << 5));
            f32x4 tA = w24[0] * hh4[0] + w24[2] * hh4[2] + w24[4] * hh4[4] + w24[6] * hh4[6];
            f32x4 tB = w24[1] * hh4[1] + w24[3] * hh4[3] + w24[5] * hh4[5] + w24[7] * hh4[7];
            f32x4 tt = tA + tB;
            float pt = (tt.x + tt.z) + (tt.y + tt.w);
            pt += dpp_movf<DPP_XOR1>(pt);            // K-halves combined
            const float own = __builtin_amdgcn_rcpf(1.f + __expf(-(pt + b2_r)));
            const float oth = dpp_movf<DPP_XOR2>(own);
            const float tau_r = qh ? oth : own;
            const float mem_r = qh ? own : oth;
            tau_p = tau_r; mem_p = mem_r;

            // head (global delay 0) from post-blend(i-1) buf[1]; full blend deferred
            const float nb0 = buf2[0].y;
            const float iw0 = tau_r * (tau_r * mem_r - 2.f * mem_r) + mem_r;  // mem*(1-tau)^2
            const float head = iw0 * (msg_p - nb0) + nb0;
            if (q == 0) s_vh[PADH(h)] = head;
        }
        __syncthreads();                            // B1 (next iter)
    }

    // ---- bulk store decode outputs (coalesced) ----
    {
        f32x4* og4 = (f32x4*)(out + b * OUT_LEN * OUT);
        og4[tid]        = s_out4[tid];
        og4[tid + NTHR] = s_out4[tid + NTHR];
    }
}

extern "C" void kernel_launch(void* const* d_in, const int* in_sizes, int n_in,
                              void* d_out, int out_size, void* d_ws, size_t ws_size,
                              hipStream_t stream) {
    const float* x       = (const float*)d_in[0];
    const int*   lengths = (const int*)  d_in[1];
    // d_in[2] = out_lengths scalar (compile-time 64)
    const float* Wm = (const float*)d_in[3];
    const float* bm = (const float*)d_in[4];
    const float* W1 = (const float*)d_in[5];
    const float* b1 = (const float*)d_in[6];
    const float* W2 = (const float*)d_in[7];
    const float* b2 = (const float*)d_in[8];
    const float* Wo = (const float*)d_in[9];
    const float* bo = (const float*)d_in[10];
    float* out = (float*)d_out;

    delayrnn_kernel<<<BATCH, NTHR, 0, stream>>>(
        x, lengths, Wm, bm, W1, b1, W2, b2, Wo, bo, out);
}